// Round 7
// baseline (204.088 us; speedup 1.0000x reference)
//
#include <hip/hip_runtime.h>

// Problem constants:
//   vol [B=2, C=16, D=96, H=96, W=96] f32
//   xyz_sample [2, 512, 3] f32
//   A [1024, 3, 3] f32
//   weight [6, 1024] f32
//   out [2, 16*512, 1024] f32  (flat: b*8388608 + (c*512+f)*1024 + k)

#define NB 2
#define NC 16
#define NS 96
#define NS3 (NS * NS * NS)
#define FEATS 512
#define NK 1024
#define PASSES 8               // 8 passes x 128 k-slots x 2 duo lanes = 1024 k

#define RVOX 8                 // staged region extent per axis (voxels)

// Swizzled LDS address for (voxel, half): 32 B/voxel, 16 KB total.
//   b128 slot bits (addr[6:4]) = {x1^y0, x0, h^z0}; h (duo) is a uniform lane
//   bit, x0/x1^y0 spread across lanes -> gather reads cover the 8 bank slots.
__device__ __forceinline__ int stage_addr(int xg, int yg, int zg, int h) {
  int v = (zg << 6) + (yg << 3) + xg;
  v ^= (yg & 1) << 1;
  return (v << 5) | (((h ^ zg) & 1) << 4);
}

__device__ __forceinline__ unsigned int bfround(float f) {
  unsigned int u = __float_as_uint(f);
  return (u + 0x7fffu + ((u >> 16) & 1u)) >> 16;  // RNE
}

#define BLO(v) __uint_as_float((v) << 16)
#define BHI(v) __uint_as_float((v) & 0xffff0000u)

// Inline function (NOT a macro: a macro param named `w` would be substituted
// into the `.w` member access — the R6 compile failure).
__device__ __forceinline__ void acc8(const uint4& u, float wt, float acc[8]) {
  acc[0] += wt * BLO(u.x);
  acc[1] += wt * BHI(u.x);
  acc[2] += wt * BLO(u.y);
  acc[3] += wt * BHI(u.y);
  acc[4] += wt * BLO(u.z);
  acc[5] += wt * BHI(u.z);
  acc[6] += wt * BLO(u.w);
  acc[7] += wt * BHI(u.w);
}

// ---------------------------------------------------------------------------
// Slow-path trilinear (rare: offset beyond staged 8^3): direct f32 gather
// from the original [B,C,D,H,W] volume, volume-OOB -> zero padding.
// ---------------------------------------------------------------------------
__device__ __forceinline__ void tri_slow(
    const float* __restrict__ vol, size_t cbase,
    float x, float y, float z, float sgn, float acc[8]) {
  float fx0 = floorf(x), fy0 = floorf(y), fz0 = floorf(z);
  int ix0 = (int)fx0, iy0 = (int)fy0, iz0 = (int)fz0;
  float tx = x - fx0, ty = y - fy0, tz = z - fz0;
  float wxa[2] = {1.0f - tx, tx};
  float wya[2] = {1.0f - ty, ty};
  float wza[2] = {1.0f - tz, tz};
#pragma unroll
  for (int dz = 0; dz < 2; dz++) {
    int zc = iz0 + dz;
    if ((unsigned)zc >= (unsigned)NS) continue;
#pragma unroll
    for (int dy = 0; dy < 2; dy++) {
      int yc = iy0 + dy;
      if ((unsigned)yc >= (unsigned)NS) continue;
      float wzy = sgn * wza[dz] * wya[dy];
#pragma unroll
      for (int dx = 0; dx < 2; dx++) {
        int xc = ix0 + dx;
        if ((unsigned)xc >= (unsigned)NS) continue;
        float w = wzy * wxa[dx];
        const float* p = vol + cbase + (((size_t)zc * NS + yc) * NS + xc);
#pragma unroll
        for (int c = 0; c < 8; c++)
          acc[c] += w * p[(size_t)c * NS3];
      }
    }
  }
}

// ---------------------------------------------------------------------------
// Fused sample kernel: one block per (b, f). Stage 8^3 x 16ch neighborhood
// (bf16, swizzled, 16 KB LDS), then 8 passes of 128 k-slots x 2 duo lanes.
// Fast path issues ALL 16 corner ds_read_b128s into registers before any
// consumption (one LDS-latency exposure per pass, not 16).
// ---------------------------------------------------------------------------
__global__ __launch_bounds__(256, 4) void sample_fused(
    const float* __restrict__ vol, const float* __restrict__ xyz,
    const float* __restrict__ A, const float* __restrict__ weight,
    float* __restrict__ out) {
  __shared__ __align__(128) unsigned char stage[RVOX * RVOX * RVOX * 32];  // 16 KB

  int n = blockIdx.x;                   // b*512 + f
  int b = n >> 9;
  int f = n & 511;
  int tid = threadIdx.x;

  const float* Xn = xyz + (size_t)n * 3;
  float bx = (Xn[0] + 1.0f) * 48.0f - 0.5f;  // W axis <- xs[0]
  float by = (Xn[1] + 1.0f) * 48.0f - 0.5f;  // H axis <- xs[1]
  float bz = (Xn[2] + 1.0f) * 48.0f - 0.5f;  // D axis <- xs[2]
  int ox0 = (int)floorf(bx) - 3;
  int oy0 = (int)floorf(by) - 3;
  int oz0 = (int)floorf(bz) - 3;

  int duo = tid & 1;                    // which 8-channel half
  int ksub = tid >> 1;                  // 0..127

  const float* An = A + (size_t)n * 9;
  float a00 = An[0], a01 = An[1], a02 = An[2];
  float a10 = An[3], a11 = An[4], a12 = An[5];
  float a20 = An[6], a21 = An[7], a22 = An[8];

  // Stage 512 voxels x 16ch as bf16, zero-filling volume-OOB voxels.
  size_t vb = (size_t)b * NC * NS3;
#pragma unroll
  for (int j = 0; j < 4; j++) {
    int w = tid + 256 * j;              // 0..1023
    int half = w & 1;
    int v = w >> 1;                     // voxel 0..511
    int xg = v & 7, yg = (v >> 3) & 7, zg = v >> 6;
    int xc = ox0 + xg, yc = oy0 + yg, zc = oz0 + zg;
    uint4 r = make_uint4(0u, 0u, 0u, 0u);
    if (((unsigned)xc < (unsigned)NS) & ((unsigned)yc < (unsigned)NS) &
        ((unsigned)zc < (unsigned)NS)) {
      const float* p = vol + vb + (size_t)(half * 8) * NS3 +
                       (((size_t)zc * NS + yc) * NS + xc);
      float f0 = p[0];
      float f1 = p[NS3];
      float f2 = p[2 * NS3];
      float f3 = p[3 * NS3];
      float f4 = p[4 * NS3];
      float f5 = p[5 * NS3];
      float f6 = p[6 * NS3];
      float f7 = p[7 * NS3];
      r.x = bfround(f0) | (bfround(f1) << 16);
      r.y = bfround(f2) | (bfround(f3) << 16);
      r.z = bfround(f4) | (bfround(f5) << 16);
      r.w = bfround(f6) | (bfround(f7) << 16);
    }
    *(uint4*)(stage + stage_addr(xg, yg, zg, half)) = r;
  }
  __syncthreads();

  size_t cbase = ((size_t)b * NC + duo * 8) * NS3;
  size_t obase = (size_t)b * (NC * FEATS * NK) +
                 (size_t)(duo * 8) * (FEATS * NK) + (size_t)f * NK;

  // Weight prefetch pipeline: wc = current pass, wn = next pass.
  float wc[6], wn[6];
#pragma unroll
  for (int q = 0; q < 6; q++) wc[q] = weight[q * NK + ksub];

  for (int pass = 0; pass < PASSES; pass++) {
    int kl = pass * 128 + ksub;
    if (pass < PASSES - 1) {
#pragma unroll
      for (int q = 0; q < 6; q++) wn[q] = weight[q * NK + kl + 128];
    }

    float acc[8] = {0.0f, 0.0f, 0.0f, 0.0f, 0.0f, 0.0f, 0.0f, 0.0f};

    // Offsets for both grids.
    float oz1 = a00 * wc[0] + a01 * wc[1] + a02 * wc[2];
    float oy1 = a10 * wc[0] + a11 * wc[1] + a12 * wc[2];
    float ox1 = a20 * wc[0] + a21 * wc[1] + a22 * wc[2];
    float oz2 = a00 * wc[3] + a01 * wc[4] + a02 * wc[5];
    float oy2 = a10 * wc[3] + a11 * wc[4] + a12 * wc[5];
    float ox2 = a20 * wc[3] + a21 * wc[4] + a22 * wc[5];
    float x1 = bx + ox1 * 48.0f, y1 = by + oy1 * 48.0f, z1 = bz + oz1 * 48.0f;
    float x2 = bx + ox2 * 48.0f, y2 = by + oy2 * 48.0f, z2 = bz + oz2 * 48.0f;

    float fx1 = floorf(x1), fy1 = floorf(y1), fz1 = floorf(z1);
    float fx2 = floorf(x2), fy2 = floorf(y2), fz2 = floorf(z2);
    int lx1 = (int)fx1 - ox0, ly1 = (int)fy1 - oy0, lz1 = (int)fz1 - oz0;
    int lx2 = (int)fx2 - ox0, ly2 = (int)fy2 - oy0, lz2 = (int)fz2 - oz0;
    bool fast =
        ((unsigned)lx1 < 7u) & ((unsigned)ly1 < 7u) & ((unsigned)lz1 < 7u) &
        ((unsigned)lx2 < 7u) & ((unsigned)ly2 < 7u) & ((unsigned)lz2 < 7u);

    if (__builtin_expect(fast, 1)) {
      // Issue ALL 16 corner reads before consuming any.
      uint4 G1[8], G2[8];
#pragma unroll
      for (int i = 0; i < 8; i++) {
        int dx = i & 1, dy = (i >> 1) & 1, dz = i >> 2;
        G1[i] = *(const uint4*)(stage +
                                stage_addr(lx1 + dx, ly1 + dy, lz1 + dz, duo));
      }
#pragma unroll
      for (int i = 0; i < 8; i++) {
        int dx = i & 1, dy = (i >> 1) & 1, dz = i >> 2;
        G2[i] = *(const uint4*)(stage +
                                stage_addr(lx2 + dx, ly2 + dy, lz2 + dz, duo));
      }

      // Corner weights (VALU work overlapping the LDS latency).
      float tx1 = x1 - fx1, ty1 = y1 - fy1, tz1 = z1 - fz1;
      float tx2 = x2 - fx2, ty2 = y2 - fy2, tz2 = z2 - fz2;
      float W1[8], W2[8];
      {
        float w00 = (1.0f - tz1) * (1.0f - ty1);
        float w01 = (1.0f - tz1) * ty1;
        float w10 = tz1 * (1.0f - ty1);
        float w11 = tz1 * ty1;
        W1[0] = w00 * (1.0f - tx1); W1[1] = w00 * tx1;
        W1[2] = w01 * (1.0f - tx1); W1[3] = w01 * tx1;
        W1[4] = w10 * (1.0f - tx1); W1[5] = w10 * tx1;
        W1[6] = w11 * (1.0f - tx1); W1[7] = w11 * tx1;
      }
      {
        float w00 = -(1.0f - tz2) * (1.0f - ty2);   // sgn = -1 folded
        float w01 = -(1.0f - tz2) * ty2;
        float w10 = -tz2 * (1.0f - ty2);
        float w11 = -tz2 * ty2;
        W2[0] = w00 * (1.0f - tx2); W2[1] = w00 * tx2;
        W2[2] = w01 * (1.0f - tx2); W2[3] = w01 * tx2;
        W2[4] = w10 * (1.0f - tx2); W2[5] = w10 * tx2;
        W2[6] = w11 * (1.0f - tx2); W2[7] = w11 * tx2;
      }

#pragma unroll
      for (int i = 0; i < 8; i++) acc8(G1[i], W1[i], acc);
#pragma unroll
      for (int i = 0; i < 8; i++) acc8(G2[i], W2[i], acc);
    } else {
      tri_slow(vol, cbase, x1, y1, z1, 1.0f, acc);
      tri_slow(vol, cbase, x2, y2, z2, -1.0f, acc);
    }

    size_t o = obase + kl;
#pragma unroll
    for (int c = 0; c < 8; c++)
      out[o + (size_t)c * (FEATS * NK)] = acc[c];

#pragma unroll
    for (int q = 0; q < 6; q++) wc[q] = wn[q];
  }
}

extern "C" void kernel_launch(void* const* d_in, const int* in_sizes, int n_in,
                              void* d_out, int out_size, void* d_ws,
                              size_t ws_size, hipStream_t stream) {
  const float* vol    = (const float*)d_in[0];
  const float* xyz    = (const float*)d_in[1];
  const float* A      = (const float*)d_in[2];
  const float* weight = (const float*)d_in[3];
  float* out = (float*)d_out;

  sample_fused<<<NB * FEATS, 256, 0, stream>>>(vol, xyz, A, weight, out);
}

// Round 8
// 201.972 us; speedup vs baseline: 1.0105x; 1.0105x over previous
//
#include <hip/hip_runtime.h>
#include <hip/hip_fp16.h>

// Problem constants:
//   vol [B=2, C=16, D=96, H=96, W=96] f32
//   xyz_sample [2, 512, 3] f32
//   A [1024, 3, 3] f32
//   weight [6, 1024] f32
//   out [2, 16*512, 1024] f32  (flat: b*8388608 + (c*512+f)*1024 + k)

#define NB 2
#define NC 16
#define NS 96
#define NS3 (NS * NS * NS)
#define FEATS 512
#define NK 1024
#define KSPLIT 2
#define KCHUNK (NK / KSPLIT)   // 512
#define PASSES 4               // 4 passes x 128 k-slots x 2 duo lanes = 512 k

#define RVOX 8                 // staged region extent per axis (voxels)

// Swizzled LDS address for (voxel, half): 32 B/voxel, 16 KB total.
//   b128 slot bits (addr[6:4]) = {x1^y0, x0, h^z0}; h (duo) is a uniform lane
//   bit, x0/x1^y0 spread across lanes -> gather reads cover the 8 bank slots.
__device__ __forceinline__ int stage_addr(int xg, int yg, int zg, int h) {
  int v = (zg << 6) + (yg << 3) + xg;
  v ^= (yg & 1) << 1;
  return (v << 5) | (((h ^ zg) & 1) << 4);
}

// Pack two f32 into f16x2 (RNE).
__device__ __forceinline__ unsigned int packh2(float lo, float hi) {
  __half2 h = __halves2half2(__float2half(lo), __float2half(hi));
  return __builtin_bit_cast(unsigned int, h);
}

// acc pair via v_fma_mix_f32: fmaf((float)f16half, w, acc) — backend folds
// the fpext into the FMA (mad-mix combine), 1 inst per channel, f32 accum.
__device__ __forceinline__ void accpair(unsigned int v, float wt,
                                        float& a0, float& a1) {
  __half2 h = __builtin_bit_cast(__half2, v);
  a0 = fmaf(__low2float(h), wt, a0);
  a1 = fmaf(__high2float(h), wt, a1);
}

__device__ __forceinline__ void acc8(const uint4& u, float wt, float acc[8]) {
  accpair(u.x, wt, acc[0], acc[1]);
  accpair(u.y, wt, acc[2], acc[3]);
  accpair(u.z, wt, acc[4], acc[5]);
  accpair(u.w, wt, acc[6], acc[7]);
}

// ---------------------------------------------------------------------------
// Duo-split trilinear. Each lane owns 8 channels (uint4 = 16B per corner);
// 2 lanes cover a sample. Fast path: LDS-staged 8^3 neighborhood
// (zero-padded => no bounds checks), swizzled addresses, f16 data consumed
// by v_fma_mix_f32. Slow path (~never, >7 sigma): direct f32 gather.
// ---------------------------------------------------------------------------
__device__ __forceinline__ void tri_duo(
    const float* __restrict__ vol, size_t cbase,   // vol + (b, duo*8) base
    const unsigned char* __restrict__ stage, int duo,
    int ox0, int oy0, int oz0,
    float x, float y, float z, float sgn, float acc[8]) {
  float fx0 = floorf(x), fy0 = floorf(y), fz0 = floorf(z);
  int ix0 = (int)fx0, iy0 = (int)fy0, iz0 = (int)fz0;
  float tx = x - fx0, ty = y - fy0, tz = z - fz0;
  float wxa[2] = {1.0f - tx, tx};
  float wya[2] = {1.0f - ty, ty};
  float wza[2] = {1.0f - tz, tz};

  int lx0 = ix0 - ox0, ly0 = iy0 - oy0, lz0 = iz0 - oz0;
  bool fast = ((unsigned)lx0 < 7u) & ((unsigned)ly0 < 7u) & ((unsigned)lz0 < 7u);

  if (__builtin_expect(fast, 1)) {
#pragma unroll
    for (int dz = 0; dz < 2; dz++) {
      float wz = sgn * wza[dz];
      int vz = lz0 + dz;
#pragma unroll
      for (int dy = 0; dy < 2; dy++) {
        float wzy = wz * wya[dy];
        int vy = ly0 + dy;
#pragma unroll
        for (int dx = 0; dx < 2; dx++) {
          float w = wzy * wxa[dx];
          int vx = lx0 + dx;
          uint4 u = *(const uint4*)(stage + stage_addr(vx, vy, vz, duo));
          acc8(u, w, acc);
        }
      }
    }
  } else {
#pragma unroll
    for (int dz = 0; dz < 2; dz++) {
      int zc = iz0 + dz;
      if ((unsigned)zc >= (unsigned)NS) continue;
#pragma unroll
      for (int dy = 0; dy < 2; dy++) {
        int yc = iy0 + dy;
        if ((unsigned)yc >= (unsigned)NS) continue;
        float wzy = sgn * wza[dz] * wya[dy];
#pragma unroll
        for (int dx = 0; dx < 2; dx++) {
          int xc = ix0 + dx;
          if ((unsigned)xc >= (unsigned)NS) continue;
          float w = wzy * wxa[dx];
          const float* p = vol + cbase + (((size_t)zc * NS + yc) * NS + xc);
#pragma unroll
          for (int c = 0; c < 8; c++)
            acc[c] += w * p[(size_t)c * NS3];
        }
      }
    }
  }
}

// ---------------------------------------------------------------------------
// Fused sample kernel: one block per (b, f, kseg). Stages the 8^3 x 16ch
// neighborhood from the f32 volume (f16 in-register), swizzled into 16 KB
// of LDS, then 4 passes of 128 k-slots x 2 duo lanes with weight prefetch.
// ---------------------------------------------------------------------------
__global__ __launch_bounds__(256) void sample_fused(
    const float* __restrict__ vol, const float* __restrict__ xyz,
    const float* __restrict__ A, const float* __restrict__ weight,
    float* __restrict__ out) {
  __shared__ __align__(128) unsigned char stage[RVOX * RVOX * RVOX * 32];  // 16 KB

  int bid = blockIdx.x;
  int kseg = bid & (KSPLIT - 1);
  int n = bid >> 1;                     // b*512 + f
  int b = n >> 9;
  int f = n & 511;
  int kbase = kseg * KCHUNK;
  int tid = threadIdx.x;

  const float* Xn = xyz + (size_t)n * 3;
  float bx = (Xn[0] + 1.0f) * 48.0f - 0.5f;  // W axis <- xs[0]
  float by = (Xn[1] + 1.0f) * 48.0f - 0.5f;  // H axis <- xs[1]
  float bz = (Xn[2] + 1.0f) * 48.0f - 0.5f;  // D axis <- xs[2]
  int ox0 = (int)floorf(bx) - 3;
  int oy0 = (int)floorf(by) - 3;
  int oz0 = (int)floorf(bz) - 3;

  int duo = tid & 1;                    // which 8-channel half
  int ksub = tid >> 1;                  // 0..127

  // A rows pre-scaled by 48: offsets land directly in voxel units.
  const float* An = A + (size_t)n * 9;
  float a00 = An[0] * 48.0f, a01 = An[1] * 48.0f, a02 = An[2] * 48.0f;
  float a10 = An[3] * 48.0f, a11 = An[4] * 48.0f, a12 = An[5] * 48.0f;
  float a20 = An[6] * 48.0f, a21 = An[7] * 48.0f, a22 = An[8] * 48.0f;

  // Stage 512 voxels x 16ch as f16, zero-filling volume-OOB voxels.
  size_t vb = (size_t)b * NC * NS3;
#pragma unroll
  for (int j = 0; j < 4; j++) {
    int w = tid + 256 * j;              // 0..1023
    int half = w & 1;
    int v = w >> 1;                     // voxel 0..511
    int xg = v & 7, yg = (v >> 3) & 7, zg = v >> 6;
    int xc = ox0 + xg, yc = oy0 + yg, zc = oz0 + zg;
    uint4 r = make_uint4(0u, 0u, 0u, 0u);
    if (((unsigned)xc < (unsigned)NS) & ((unsigned)yc < (unsigned)NS) &
        ((unsigned)zc < (unsigned)NS)) {
      const float* p = vol + vb + (size_t)(half * 8) * NS3 +
                       (((size_t)zc * NS + yc) * NS + xc);
      float f0 = p[0];
      float f1 = p[NS3];
      float f2 = p[2 * NS3];
      float f3 = p[3 * NS3];
      float f4 = p[4 * NS3];
      float f5 = p[5 * NS3];
      float f6 = p[6 * NS3];
      float f7 = p[7 * NS3];
      r.x = packh2(f0, f1);
      r.y = packh2(f2, f3);
      r.z = packh2(f4, f5);
      r.w = packh2(f6, f7);
    }
    *(uint4*)(stage + stage_addr(xg, yg, zg, half)) = r;
  }
  __syncthreads();

  size_t cbase = ((size_t)b * NC + duo * 8) * NS3;
  size_t obase = (size_t)b * (NC * FEATS * NK) +
                 (size_t)(duo * 8) * (FEATS * NK) + (size_t)f * NK + kbase;

  // Weight prefetch pipeline: wc = current pass, wn = next pass.
  float wc[6], wn[6];
#pragma unroll
  for (int q = 0; q < 6; q++) wc[q] = weight[q * NK + kbase + ksub];

  for (int pass = 0; pass < PASSES; pass++) {
    int kl = pass * 128 + ksub;
    if (pass < PASSES - 1) {
#pragma unroll
      for (int q = 0; q < 6; q++) wn[q] = weight[q * NK + kbase + kl + 128];
    }

    float acc[8] = {0.0f, 0.0f, 0.0f, 0.0f, 0.0f, 0.0f, 0.0f, 0.0f};

    {  // grid 1 (+)
      float oz = a00 * wc[0] + a01 * wc[1] + a02 * wc[2];
      float oy = a10 * wc[0] + a11 * wc[1] + a12 * wc[2];
      float ox = a20 * wc[0] + a21 * wc[1] + a22 * wc[2];
      tri_duo(vol, cbase, stage, duo, ox0, oy0, oz0, bx + ox, by + oy,
              bz + oz, 1.0f, acc);
    }
    {  // grid 2 (-)
      float oz = a00 * wc[3] + a01 * wc[4] + a02 * wc[5];
      float oy = a10 * wc[3] + a11 * wc[4] + a12 * wc[5];
      float ox = a20 * wc[3] + a21 * wc[4] + a22 * wc[5];
      tri_duo(vol, cbase, stage, duo, ox0, oy0, oz0, bx + ox, by + oy,
              bz + oz, -1.0f, acc);
    }

    size_t o = obase + kl;
#pragma unroll
    for (int c = 0; c < 8; c++)
      out[o + (size_t)c * (FEATS * NK)] = acc[c];

#pragma unroll
    for (int q = 0; q < 6; q++) wc[q] = wn[q];
  }
}

extern "C" void kernel_launch(void* const* d_in, const int* in_sizes, int n_in,
                              void* d_out, int out_size, void* d_ws,
                              size_t ws_size, hipStream_t stream) {
  const float* vol    = (const float*)d_in[0];
  const float* xyz    = (const float*)d_in[1];
  const float* A      = (const float*)d_in[2];
  const float* weight = (const float*)d_in[3];
  float* out = (float*)d_out;

  sample_fused<<<NB * FEATS * KSPLIT, 256, 0, stream>>>(vol, xyz, A, weight,
                                                        out);
}

// Round 9
// 197.571 us; speedup vs baseline: 1.0330x; 1.0223x over previous
//
#include <hip/hip_runtime.h>
#include <hip/hip_fp16.h>

// Problem constants:
//   vol [B=2, C=16, D=96, H=96, W=96] f32
//   xyz_sample [2, 512, 3] f32
//   A [1024, 3, 3] f32
//   weight [6, 1024] f32
//   out [2, 16*512, 1024] f32  (flat: b*8388608 + (c*512+f)*1024 + k)

#define NB 2
#define NC 16
#define NS 96
#define NS3 (NS * NS * NS)
#define FEATS 512
#define NK 1024
#define PASSES 4               // 4 passes x 256 k-slots x 2 duo lanes = 1024 k

#define RX 10                  // x extent (even-aligned origin, covers +-)
#define RY 8
#define RZ 8
#define NVOX (RX * RY * RZ)    // 640 voxels, 32 B each -> 20 KB LDS

// LDS address for (local voxel, channel-half). 32 B/voxel.
//   v = (z*8+y)*10+x. addr[4] = h^z0, addr[5] = v&1 = x&1,
//   addr[6] = (2*row+x)&2. The 8 corners of a sample flip dx->bit5,
//   dy->bit6, dz->bit4: all 8 b128 slots covered per sample.
__device__ __forceinline__ int stage_addr(int xg, int yg, int zg, int h) {
  int row = (zg << 3) + yg;
  int v = row * RX + xg;
  return (v << 5) | (((h ^ zg) & 1) << 4);
}

// Pack two f32 into f16x2 (RNE).
__device__ __forceinline__ unsigned int packh2(float lo, float hi) {
  __half2 h = __halves2half2(__float2half(lo), __float2half(hi));
  return __builtin_bit_cast(unsigned int, h);
}

// acc pair via v_fma_mix_f32: fmaf((float)f16half, w, acc).
__device__ __forceinline__ void accpair(unsigned int v, float wt,
                                        float& a0, float& a1) {
  __half2 h = __builtin_bit_cast(__half2, v);
  a0 = fmaf(__low2float(h), wt, a0);
  a1 = fmaf(__high2float(h), wt, a1);
}

__device__ __forceinline__ void acc8(const uint4& u, float wt, float acc[8]) {
  accpair(u.x, wt, acc[0], acc[1]);
  accpair(u.y, wt, acc[2], acc[3]);
  accpair(u.z, wt, acc[4], acc[5]);
  accpair(u.w, wt, acc[6], acc[7]);
}

// ---------------------------------------------------------------------------
// Duo-split trilinear. Fast path: LDS-staged neighborhood (zero-padded).
// Slow path (~never, >7 sigma): direct f32 gather with volume-OOB checks.
// ---------------------------------------------------------------------------
__device__ __forceinline__ void tri_duo(
    const float* __restrict__ vol, size_t cbase,   // vol + (b, duo*8) base
    const unsigned char* __restrict__ stage, int duo,
    int ox0, int oy0, int oz0,
    float x, float y, float z, float sgn, float acc[8]) {
  float fx0 = floorf(x), fy0 = floorf(y), fz0 = floorf(z);
  int ix0 = (int)fx0, iy0 = (int)fy0, iz0 = (int)fz0;
  float tx = x - fx0, ty = y - fy0, tz = z - fz0;
  float wxa[2] = {1.0f - tx, tx};
  float wya[2] = {1.0f - ty, ty};
  float wza[2] = {1.0f - tz, tz};

  int lx0 = ix0 - ox0, ly0 = iy0 - oy0, lz0 = iz0 - oz0;
  bool fast = ((unsigned)lx0 < (unsigned)(RX - 1)) &
              ((unsigned)ly0 < (unsigned)(RY - 1)) &
              ((unsigned)lz0 < (unsigned)(RZ - 1));

  if (__builtin_expect(fast, 1)) {
#pragma unroll
    for (int dz = 0; dz < 2; dz++) {
      float wz = sgn * wza[dz];
      int vz = lz0 + dz;
#pragma unroll
      for (int dy = 0; dy < 2; dy++) {
        float wzy = wz * wya[dy];
        int vy = ly0 + dy;
#pragma unroll
        for (int dx = 0; dx < 2; dx++) {
          float w = wzy * wxa[dx];
          int vx = lx0 + dx;
          uint4 u = *(const uint4*)(stage + stage_addr(vx, vy, vz, duo));
          acc8(u, w, acc);
        }
      }
    }
  } else {
#pragma unroll
    for (int dz = 0; dz < 2; dz++) {
      int zc = iz0 + dz;
      if ((unsigned)zc >= (unsigned)NS) continue;
#pragma unroll
      for (int dy = 0; dy < 2; dy++) {
        int yc = iy0 + dy;
        if ((unsigned)yc >= (unsigned)NS) continue;
        float wzy = sgn * wza[dz] * wya[dy];
#pragma unroll
        for (int dx = 0; dx < 2; dx++) {
          int xc = ix0 + dx;
          if ((unsigned)xc >= (unsigned)NS) continue;
          float w = wzy * wxa[dx];
          const float* p = vol + cbase + (((size_t)zc * NS + yc) * NS + xc);
#pragma unroll
          for (int c = 0; c < 8; c++)
            acc[c] += w * p[(size_t)c * NS3];
        }
      }
    }
  }
}

// ---------------------------------------------------------------------------
// Fused sample kernel: ONE block (512 thr) per (b, f) — region staged once.
// Staging: task = (x-pair, half); thread loads 8 channel-planes x float2
// (8 B/lane coalesced), packs f16, writes 2x ds_write_b128 in final layout.
// Then 4 passes of 256 k-slots x 2 duo lanes, f16 fma_mix accumulate.
// ---------------------------------------------------------------------------
__global__ __launch_bounds__(512, 4) void sample_fused(
    const float* __restrict__ vol, const float* __restrict__ xyz,
    const float* __restrict__ A, const float* __restrict__ weight,
    float* __restrict__ out) {
  __shared__ __align__(128) unsigned char stage[NVOX * 32];  // 20 KB

  int n = blockIdx.x;                   // b*512 + f
  int b = n >> 9;
  int f = n & 511;
  int tid = threadIdx.x;

  const float* Xn = xyz + (size_t)n * 3;
  float bx = (Xn[0] + 1.0f) * 48.0f - 0.5f;  // W axis <- xs[0]
  float by = (Xn[1] + 1.0f) * 48.0f - 0.5f;  // H axis <- xs[1]
  float bz = (Xn[2] + 1.0f) * 48.0f - 0.5f;  // D axis <- xs[2]
  int ox0 = ((int)floorf(bx) - 3) & ~1;      // even-aligned, extent 10
  int oy0 = (int)floorf(by) - 3;
  int oz0 = (int)floorf(bz) - 3;

  int duo = tid & 1;                    // which 8-channel half
  int ksub = tid >> 1;                  // 0..255

  // A rows pre-scaled by 48: offsets land directly in voxel units.
  const float* An = A + (size_t)n * 9;
  float a00 = An[0] * 48.0f, a01 = An[1] * 48.0f, a02 = An[2] * 48.0f;
  float a10 = An[3] * 48.0f, a11 = An[4] * 48.0f, a12 = An[5] * 48.0f;
  float a20 = An[6] * 48.0f, a21 = An[7] * 48.0f, a22 = An[8] * 48.0f;

  // ---- Stage 640 voxels x 16 ch as f16 (zero-fill volume-OOB). ----
  // 640 tasks: t = (x-pair pv, half). 8 float2 loads per task.
  size_t vb = (size_t)b * NC * NS3;
  for (int t = tid; t < NVOX; t += 512) {
    int half = t & 1;
    int pv = t >> 1;                    // 0..319
    int px = pv % 5;
    int rowi = pv / 5;                  // 0..63
    int yg = rowi & 7, zg = rowi >> 3;
    int xg = px << 1;
    int xc = ox0 + xg, yc = oy0 + yg, zc = oz0 + zg;
    bool rowv = ((unsigned)yc < (unsigned)NS) & ((unsigned)zc < (unsigned)NS);
    bool v0 = rowv & ((unsigned)xc < (unsigned)NS);
    bool v1 = rowv & ((unsigned)(xc + 1) < (unsigned)NS);
    const float* pc = vol + vb + (size_t)(half * 8) * NS3 +
                      (ptrdiff_t)(((long)zc * NS + yc) * NS + xc);
    float av[8], bv[8];
    if (v0 & v1) {
#pragma unroll
      for (int c = 0; c < 8; c++) {
        float2 f2 = *(const float2*)(pc + (size_t)c * NS3);
        av[c] = f2.x;
        bv[c] = f2.y;
      }
    } else {
#pragma unroll
      for (int c = 0; c < 8; c++) {
        av[c] = v0 ? pc[(size_t)c * NS3] : 0.0f;
        bv[c] = v1 ? pc[(size_t)c * NS3 + 1] : 0.0f;
      }
    }
    uint4 u0 = make_uint4(packh2(av[0], av[1]), packh2(av[2], av[3]),
                          packh2(av[4], av[5]), packh2(av[6], av[7]));
    uint4 u1 = make_uint4(packh2(bv[0], bv[1]), packh2(bv[2], bv[3]),
                          packh2(bv[4], bv[5]), packh2(bv[6], bv[7]));
    *(uint4*)(stage + stage_addr(xg, yg, zg, half)) = u0;
    *(uint4*)(stage + stage_addr(xg + 1, yg, zg, half)) = u1;
  }
  __syncthreads();

  size_t cbase = ((size_t)b * NC + duo * 8) * NS3;
  size_t obase = (size_t)b * (NC * FEATS * NK) +
                 (size_t)(duo * 8) * (FEATS * NK) + (size_t)f * NK;

  // Weight prefetch pipeline: wc = current pass, wn = next pass.
  float wc[6], wn[6];
#pragma unroll
  for (int q = 0; q < 6; q++) wc[q] = weight[q * NK + ksub];

  for (int pass = 0; pass < PASSES; pass++) {
    int kl = pass * 256 + ksub;
    if (pass < PASSES - 1) {
#pragma unroll
      for (int q = 0; q < 6; q++) wn[q] = weight[q * NK + kl + 256];
    }

    float acc[8] = {0.0f, 0.0f, 0.0f, 0.0f, 0.0f, 0.0f, 0.0f, 0.0f};

    {  // grid 1 (+)
      float oz = a00 * wc[0] + a01 * wc[1] + a02 * wc[2];
      float oy = a10 * wc[0] + a11 * wc[1] + a12 * wc[2];
      float ox = a20 * wc[0] + a21 * wc[1] + a22 * wc[2];
      tri_duo(vol, cbase, stage, duo, ox0, oy0, oz0, bx + ox, by + oy,
              bz + oz, 1.0f, acc);
    }
    {  // grid 2 (-)
      float oz = a00 * wc[3] + a01 * wc[4] + a02 * wc[5];
      float oy = a10 * wc[3] + a11 * wc[4] + a12 * wc[5];
      float ox = a20 * wc[3] + a21 * wc[4] + a22 * wc[5];
      tri_duo(vol, cbase, stage, duo, ox0, oy0, oz0, bx + ox, by + oy,
              bz + oz, -1.0f, acc);
    }

    size_t o = obase + kl;
#pragma unroll
    for (int c = 0; c < 8; c++)
      out[o + (size_t)c * (FEATS * NK)] = acc[c];

#pragma unroll
    for (int q = 0; q < 6; q++) wc[q] = wn[q];
  }
}

extern "C" void kernel_launch(void* const* d_in, const int* in_sizes, int n_in,
                              void* d_out, int out_size, void* d_ws,
                              size_t ws_size, hipStream_t stream) {
  const float* vol    = (const float*)d_in[0];
  const float* xyz    = (const float*)d_in[1];
  const float* A      = (const float*)d_in[2];
  const float* weight = (const float*)d_in[3];
  float* out = (float*)d_out;

  sample_fused<<<NB * FEATS, 512, 0, stream>>>(vol, xyz, A, weight, out);
}

// Round 10
// 197.050 us; speedup vs baseline: 1.0357x; 1.0026x over previous
//
#include <hip/hip_runtime.h>
#include <hip/hip_fp16.h>

// Problem constants:
//   vol [B=2, C=16, D=96, H=96, W=96] f32
//   xyz_sample [2, 512, 3] f32
//   A [1024, 3, 3] f32
//   weight [6, 1024] f32
//   out [2, 16*512, 1024] f32  (flat: b*8388608 + (c*512+f)*1024 + k)

#define NB 2
#define NC 16
#define NS 96
#define NS3 (NS * NS * NS)
#define FEATS 512
#define NK 1024
#define PASSES 4               // 4 passes x 256 k-slots x 2 duo lanes = 1024 k

#define RX 10                  // x extent (even-aligned origin)
#define RY 8
#define RZ 8
#define NVOX (RX * RY * RZ)    // 640 voxels, 32 B each -> 20 KB LDS

// LDS address for (local voxel, channel-half). 32 B/voxel.
//   v = ((z*8+y)*10+x). addr[4] = h^z0. Corner steps from a base address:
//   dx -> +32, dy -> +320, dz -> +2560 then XOR 16 (bit4 flip, no carry:
//   2560 has no bit4).
__device__ __forceinline__ int stage_addr(int xg, int yg, int zg, int h) {
  int row = (zg << 3) + yg;
  int v = row * RX + xg;
  return (v << 5) | (((h ^ zg) & 1) << 4);
}

// Pack two f32 into f16x2 (RNE).
__device__ __forceinline__ unsigned int packh2(float lo, float hi) {
  __half2 h = __halves2half2(__float2half(lo), __float2half(hi));
  return __builtin_bit_cast(unsigned int, h);
}

// Forced v_fma_mix_f32: acc += (float)f16half(v) * wt, 1 inst per MAC.
// op_sel_hi:[1,0,0] marks src0 as packed f16; op_sel picks lo/hi half.
__device__ __forceinline__ void accpair(unsigned int v, float wt,
                                        float& a0, float& a1) {
  asm("v_fma_mix_f32 %0, %1, %2, %0 op_sel_hi:[1,0,0]"
      : "+v"(a0)
      : "v"(v), "v"(wt));
  asm("v_fma_mix_f32 %0, %1, %2, %0 op_sel:[1,0,0] op_sel_hi:[1,0,0]"
      : "+v"(a1)
      : "v"(v), "v"(wt));
}

__device__ __forceinline__ void acc8(const uint4& u, float wt, float acc[8]) {
  accpair(u.x, wt, acc[0], acc[1]);
  accpair(u.y, wt, acc[2], acc[3]);
  accpair(u.z, wt, acc[4], acc[5]);
  accpair(u.w, wt, acc[6], acc[7]);
}

// ---------------------------------------------------------------------------
// Duo-split trilinear. Fast path: LDS-staged neighborhood (zero-padded),
// incremental corner addressing, forced fma_mix accumulate. Slow path
// (~never, >7 sigma): direct f32 gather with volume-OOB checks.
// ---------------------------------------------------------------------------
__device__ __forceinline__ void tri_duo(
    const float* __restrict__ vol, size_t cbase,   // vol + (b, duo*8) base
    const unsigned char* __restrict__ stage, int duo,
    int ox0, int oy0, int oz0,
    float x, float y, float z, float sgn, float acc[8]) {
  float fx0 = floorf(x), fy0 = floorf(y), fz0 = floorf(z);
  int ix0 = (int)fx0, iy0 = (int)fy0, iz0 = (int)fz0;
  float tx = x - fx0, ty = y - fy0, tz = z - fz0;

  int lx0 = ix0 - ox0, ly0 = iy0 - oy0, lz0 = iz0 - oz0;
  bool fast = ((unsigned)lx0 < (unsigned)(RX - 1)) &
              ((unsigned)ly0 < (unsigned)(RY - 1)) &
              ((unsigned)lz0 < (unsigned)(RZ - 1));

  if (__builtin_expect(fast, 1)) {
    // Corner weights, sign folded. Index = dx + 2*dy + 4*dz.
    float w00 = sgn * (1.0f - tz) * (1.0f - ty);
    float w01 = sgn * (1.0f - tz) * ty;
    float w10 = sgn * tz * (1.0f - ty);
    float w11 = sgn * tz * ty;
    float W0 = w00 * (1.0f - tx), W1 = w00 * tx;
    float W2 = w01 * (1.0f - tx), W3 = w01 * tx;
    float W4 = w10 * (1.0f - tx), W5 = w10 * tx;
    float W6 = w11 * (1.0f - tx), W7 = w11 * tx;

    int a0 = stage_addr(lx0, ly0, lz0, duo);
    int a1 = (a0 + 2560) ^ 16;          // dz=1 plane (bit4 flips with z0)
    uint4 u;
    u = *(const uint4*)(stage + a0);        acc8(u, W0, acc);
    u = *(const uint4*)(stage + a0 + 32);   acc8(u, W1, acc);
    u = *(const uint4*)(stage + a0 + 320);  acc8(u, W2, acc);
    u = *(const uint4*)(stage + a0 + 352);  acc8(u, W3, acc);
    u = *(const uint4*)(stage + a1);        acc8(u, W4, acc);
    u = *(const uint4*)(stage + a1 + 32);   acc8(u, W5, acc);
    u = *(const uint4*)(stage + a1 + 320);  acc8(u, W6, acc);
    u = *(const uint4*)(stage + a1 + 352);  acc8(u, W7, acc);
  } else {
    float wxa[2] = {1.0f - tx, tx};
    float wya[2] = {1.0f - ty, ty};
    float wza[2] = {1.0f - tz, tz};
#pragma unroll
    for (int dz = 0; dz < 2; dz++) {
      int zc = iz0 + dz;
      if ((unsigned)zc >= (unsigned)NS) continue;
#pragma unroll
      for (int dy = 0; dy < 2; dy++) {
        int yc = iy0 + dy;
        if ((unsigned)yc >= (unsigned)NS) continue;
        float wzy = sgn * wza[dz] * wya[dy];
#pragma unroll
        for (int dx = 0; dx < 2; dx++) {
          int xc = ix0 + dx;
          if ((unsigned)xc >= (unsigned)NS) continue;
          float w = wzy * wxa[dx];
          const float* p = vol + cbase + (((size_t)zc * NS + yc) * NS + xc);
#pragma unroll
          for (int c = 0; c < 8; c++)
            acc[c] += w * p[(size_t)c * NS3];
        }
      }
    }
  }
}

// ---------------------------------------------------------------------------
// Fused sample kernel: ONE block (512 thr) per (b, f) — region staged once.
// Staging: task = (x-pair, half); thread loads 8 channel-planes x float2
// (8 B/lane coalesced), packs f16, writes 2x ds_write_b128 in final layout.
// Then 4 passes of 256 k-slots x 2 duo lanes, forced fma_mix accumulate.
// ---------------------------------------------------------------------------
__global__ __launch_bounds__(512, 4) void sample_fused(
    const float* __restrict__ vol, const float* __restrict__ xyz,
    const float* __restrict__ A, const float* __restrict__ weight,
    float* __restrict__ out) {
  __shared__ __align__(128) unsigned char stage[NVOX * 32];  // 20 KB

  int n = blockIdx.x;                   // b*512 + f
  int b = n >> 9;
  int f = n & 511;
  int tid = threadIdx.x;

  const float* Xn = xyz + (size_t)n * 3;
  float bx = (Xn[0] + 1.0f) * 48.0f - 0.5f;  // W axis <- xs[0]
  float by = (Xn[1] + 1.0f) * 48.0f - 0.5f;  // H axis <- xs[1]
  float bz = (Xn[2] + 1.0f) * 48.0f - 0.5f;  // D axis <- xs[2]
  int ox0 = ((int)floorf(bx) - 3) & ~1;      // even-aligned, extent 10
  int oy0 = (int)floorf(by) - 3;
  int oz0 = (int)floorf(bz) - 3;

  int duo = tid & 1;                    // which 8-channel half
  int ksub = tid >> 1;                  // 0..255

  // A rows pre-scaled by 48: offsets land directly in voxel units.
  const float* An = A + (size_t)n * 9;
  float a00 = An[0] * 48.0f, a01 = An[1] * 48.0f, a02 = An[2] * 48.0f;
  float a10 = An[3] * 48.0f, a11 = An[4] * 48.0f, a12 = An[5] * 48.0f;
  float a20 = An[6] * 48.0f, a21 = An[7] * 48.0f, a22 = An[8] * 48.0f;

  // ---- Stage 640 voxels x 16 ch as f16 (zero-fill volume-OOB). ----
  size_t vb = (size_t)b * NC * NS3;
  for (int t = tid; t < NVOX; t += 512) {
    int half = t & 1;
    int pv = t >> 1;                    // 0..319
    int px = pv % 5;
    int rowi = pv / 5;                  // 0..63
    int yg = rowi & 7, zg = rowi >> 3;
    int xg = px << 1;
    int xc = ox0 + xg, yc = oy0 + yg, zc = oz0 + zg;
    bool rowv = ((unsigned)yc < (unsigned)NS) & ((unsigned)zc < (unsigned)NS);
    bool v0 = rowv & ((unsigned)xc < (unsigned)NS);
    bool v1 = rowv & ((unsigned)(xc + 1) < (unsigned)NS);
    const float* pc = vol + vb + (size_t)(half * 8) * NS3 +
                      (ptrdiff_t)(((long)zc * NS + yc) * NS + xc);
    float av[8], bv[8];
    if (v0 & v1) {
#pragma unroll
      for (int c = 0; c < 8; c++) {
        float2 f2 = *(const float2*)(pc + (size_t)c * NS3);
        av[c] = f2.x;
        bv[c] = f2.y;
      }
    } else {
#pragma unroll
      for (int c = 0; c < 8; c++) {
        av[c] = v0 ? pc[(size_t)c * NS3] : 0.0f;
        bv[c] = v1 ? pc[(size_t)c * NS3 + 1] : 0.0f;
      }
    }
    uint4 u0 = make_uint4(packh2(av[0], av[1]), packh2(av[2], av[3]),
                          packh2(av[4], av[5]), packh2(av[6], av[7]));
    uint4 u1 = make_uint4(packh2(bv[0], bv[1]), packh2(bv[2], bv[3]),
                          packh2(bv[4], bv[5]), packh2(bv[6], bv[7]));
    *(uint4*)(stage + stage_addr(xg, yg, zg, half)) = u0;
    *(uint4*)(stage + stage_addr(xg + 1, yg, zg, half)) = u1;
  }
  __syncthreads();

  size_t cbase = ((size_t)b * NC + duo * 8) * NS3;
  size_t obase = (size_t)b * (NC * FEATS * NK) +
                 (size_t)(duo * 8) * (FEATS * NK) + (size_t)f * NK;

  // Weight prefetch pipeline: wc = current pass, wn = next pass.
  float wc[6], wn[6];
#pragma unroll
  for (int q = 0; q < 6; q++) wc[q] = weight[q * NK + ksub];

  for (int pass = 0; pass < PASSES; pass++) {
    int kl = pass * 256 + ksub;
    if (pass < PASSES - 1) {
#pragma unroll
      for (int q = 0; q < 6; q++) wn[q] = weight[q * NK + kl + 256];
    }

    float acc[8] = {0.0f, 0.0f, 0.0f, 0.0f, 0.0f, 0.0f, 0.0f, 0.0f};

    {  // grid 1 (+)
      float oz = a00 * wc[0] + a01 * wc[1] + a02 * wc[2];
      float oy = a10 * wc[0] + a11 * wc[1] + a12 * wc[2];
      float ox = a20 * wc[0] + a21 * wc[1] + a22 * wc[2];
      tri_duo(vol, cbase, stage, duo, ox0, oy0, oz0, bx + ox, by + oy,
              bz + oz, 1.0f, acc);
    }
    {  // grid 2 (-)
      float oz = a00 * wc[3] + a01 * wc[4] + a02 * wc[5];
      float oy = a10 * wc[3] + a11 * wc[4] + a12 * wc[5];
      float ox = a20 * wc[3] + a21 * wc[4] + a22 * wc[5];
      tri_duo(vol, cbase, stage, duo, ox0, oy0, oz0, bx + ox, by + oy,
              bz + oz, -1.0f, acc);
    }

    size_t o = obase + kl;
#pragma unroll
    for (int c = 0; c < 8; c++)
      out[o + (size_t)c * (FEATS * NK)] = acc[c];

#pragma unroll
    for (int q = 0; q < 6; q++) wc[q] = wn[q];
  }
}

extern "C" void kernel_launch(void* const* d_in, const int* in_sizes, int n_in,
                              void* d_out, int out_size, void* d_ws,
                              size_t ws_size, hipStream_t stream) {
  const float* vol    = (const float*)d_in[0];
  const float* xyz    = (const float*)d_in[1];
  const float* A      = (const float*)d_in[2];
  const float* weight = (const float*)d_in[3];
  float* out = (float*)d_out;

  sample_fused<<<NB * FEATS, 512, 0, stream>>>(vol, xyz, A, weight, out);
}